// Round 15
// baseline (1099.324 us; speedup 1.0000x reference)
//
#include <hip/hip_runtime.h>
#include <hip/hip_bf16.h>
#include <hip/hip_cooperative_groups.h>

namespace cg = cooperative_groups;

#define NROW 50000
#define NCOL 50000
#define DDIM 128
#define CAP  32   // slots per destination row

typedef __bf16 bf16_t;
typedef __bf16 bf16x2 __attribute__((ext_vector_type(2)));
typedef __bf16 bf16x8 __attribute__((ext_vector_type(8)));
typedef float  f32x4  __attribute__((ext_vector_type(4)));

__device__ __forceinline__ float lrelu(float v) { return v >= 0.f ? v : 0.01f * v; }

__device__ __forceinline__ float ldf(const void* p, size_t i, bool f) {
    return f ? ((const float*)p)[i] : (float)((const bf16_t*)p)[i];
}

// fi: >=0 -> flags[fi]; -1 -> forced f32; -2 -> forced bf16
__device__ __forceinline__ bool dtf(const int* flags, int fi) {
    return (fi == -1) ? true : (fi == -2) ? false : (flags[fi] != 0);
}

struct TensorTab { const void* p[18]; int n[18]; };
struct WPtrs { const void* W[4]; int fi[4]; };

// ---------------- shared device helpers ------------------------------------
__device__ __forceinline__ void fill_edges(
    int e, const int* __restrict__ dst, const int* __restrict__ srcArr,
    const void* __restrict__ wArr, int nE, int* __restrict__ counts,
    int2* __restrict__ slots2, int* __restrict__ ovCnt,
    int* __restrict__ ovList, bool fW)
{
    if (e >= nE) return;
    int d = dst[e];
    int pos = atomicAdd(&counts[d], 1);
    if (pos < CAP) {
        int2 pk;
        pk.x = srcArr[e];
        pk.y = __float_as_int(ldf(wArr, e, fW));
        slots2[(size_t)d * CAP + pos] = pk;
    } else {
        int k = atomicAdd(ovCnt, 1);         // capacity == nE
        ovList[k] = e;
    }
}

__device__ __forceinline__ void prep_one(WPtrs P, const int* flags,
                                         __bf16* wfp, int slot)
{
    if (slot >= 4 * 2048) return;
    int m = slot >> 11, sIdx = slot & 2047;
    bool f = flags[P.fi[m]] != 0;
    int l = sIdx & 63, combo = sIdx >> 6;
    int ct = combo >> 2, kk = combo & 3;
    int col  = ct * 16 + (l & 15);
    int krow = kk * 32 + (l >> 4) * 8;
    bf16x8 v;
#pragma unroll
    for (int j = 0; j < 8; ++j)
        v[j] = (__bf16)ldf(P.W[m], (size_t)(krow + j) * DDIM + col, f);
    ((bf16x8*)wfp)[slot] = v;
}

__device__ __forceinline__ void convert_one(const void* __restrict__ feat,
                                            __bf16* __restrict__ cbuf,
                                            int i, int n8, bool f)
{
    if (i >= n8) return;
    bf16x8 v;
    if (f) {
        f32x4 a = ((const f32x4*)feat)[i * 2];
        f32x4 c = ((const f32x4*)feat)[i * 2 + 1];
#pragma unroll
        for (int j = 0; j < 4; ++j) { v[j] = (__bf16)a[j]; v[j + 4] = (__bf16)c[j]; }
    } else {
        v = ((const bf16x8*)feat)[i];
    }
    ((bf16x8*)cbuf)[i] = v;
}

// segsum over rows, grid-stride by seg-block (4 rows/block of 256t)
__device__ void seg_rows(
    int bid0, int strideB, const __bf16* __restrict__ gsrc,
    const int* __restrict__ counts, const int2* __restrict__ slots2,
    float* __restrict__ agg, int nRows,
    const int* __restrict__ srcArr, const int* __restrict__ dstArr,
    const void* __restrict__ wArr, const int* __restrict__ ovList,
    const int* __restrict__ ovCount, const int* __restrict__ flags, int fiW,
    int tid)
{
    const int segBlocks = (nRows + 3) >> 2;
    const int lane = tid & 63;
    const bf16x2* fb = (const bf16x2*)gsrc;
    for (int b = bid0; b < segBlocks; b += strideB) {
        int row = b * 4 + (tid >> 6);
        if (row >= nRows) continue;
        int cntRaw = counts[row];
        int cnt = cntRaw > CAP ? CAP : cntRaw;
        int sr = 0; float wv = 0.f;
        if (lane < cnt) {
            int2 pk = slots2[(size_t)row * CAP + lane];
            sr = pk.x;
            wv = __int_as_float(pk.y);
        }
        float2* ap = (float2*)(agg + (size_t)row * DDIM) + lane;
        float2 acc0 = {0.f, 0.f}, acc1 = {0.f, 0.f};
        int i = 0;
        for (; i + 4 <= cnt; i += 4) {
            int   a0 = __shfl(sr, i),     a1 = __shfl(sr, i + 1);
            int   a2 = __shfl(sr, i + 2), a3 = __shfl(sr, i + 3);
            float w0 = __shfl(wv, i),     w1 = __shfl(wv, i + 1);
            float w2 = __shfl(wv, i + 2), w3 = __shfl(wv, i + 3);
            bf16x2 v0 = fb[(size_t)a0 * 64 + lane];
            bf16x2 v1 = fb[(size_t)a1 * 64 + lane];
            bf16x2 v2 = fb[(size_t)a2 * 64 + lane];
            bf16x2 v3 = fb[(size_t)a3 * 64 + lane];
            acc0.x += (float)v0[0] * w0; acc0.y += (float)v0[1] * w0;
            acc1.x += (float)v1[0] * w1; acc1.y += (float)v1[1] * w1;
            acc0.x += (float)v2[0] * w2; acc0.y += (float)v2[1] * w2;
            acc1.x += (float)v3[0] * w3; acc1.y += (float)v3[1] * w3;
        }
        for (; i < cnt; ++i) {
            int   a0 = __shfl(sr, i);
            float w0 = __shfl(wv, i);
            bf16x2 v0 = fb[(size_t)a0 * 64 + lane];
            acc0.x += (float)v0[0] * w0; acc0.y += (float)v0[1] * w0;
        }
        if (cntRaw > CAP) {                  // rare: exact overflow scan
            const bool fW = dtf(flags, fiW);
            int nOv = *ovCount;
            for (int k = 0; k < nOv; ++k) {
                int e = ovList[k];
                if (dstArr[e] == row) {
                    int s = srcArr[e];
                    float wf = ldf(wArr, e, fW);
                    bf16x2 v = fb[(size_t)s * 64 + lane];
                    acc0.x += (float)v[0] * wf; acc0.y += (float)v[1] * wf;
                }
            }
        }
        acc0.x += acc1.x; acc0.y += acc1.y;
        *ap = acc0;
    }
}

// column-split MLP tile loop, grid-stride (16 rows/tile, 256t blocks)
template <bool RESIDUAL, bool HOUT>
__device__ void mlp_tiles(
    int bid0, int strideB, __bf16* At, __bf16* H1,
    const void* __restrict__ feat, const float* __restrict__ agg,
    const void* __restrict__ b1, const void* __restrict__ b2,
    const void* __restrict__ epsp, float* __restrict__ out, int N,
    const int* __restrict__ flags, int fiFeat, int fiB1, int fiB2, int fiEps,
    const __bf16* __restrict__ pW1, const __bf16* __restrict__ pW2,
    __bf16* __restrict__ hout, int tid)
{
    const int tiles = (N + 15) >> 4;
    const bool fF  = flags[fiFeat] != 0;
    const bool fB1 = flags[fiB1] != 0;
    const bool fB2 = flags[fiB2] != 0;
    const bool fE  = flags[fiEps] != 0;
    const int lane = tid & 63;
    const int wave = tid >> 6;
    const int quad = lane >> 4;
    const int r    = lane & 15;
    const float eps1 = 1.f + ldf(epsp, 0, fE);
    const int ct0 = wave * 2, ct1 = ct0 + 1;
    const bf16x8* pw1v = (const bf16x8*)pW1;
    const bf16x8* pw2v = (const bf16x8*)pW2;

    for (int b = bid0; b < tiles; b += strideB) {
        const int rowBase = b * 16;
        {
            int row = tid >> 4;
            int k0  = (tid & 15) * 8;
            int g   = rowBase + row;
            bf16x8 av;
            if (g < N) {
                size_t base = (size_t)g * DDIM + k0;
                const f32x4* gp = (const f32x4*)(agg + base);
                f32x4 g0 = gp[0], g1 = gp[1];
                if (fF) {
                    const f32x4* fp = (const f32x4*)((const float*)feat + base);
                    f32x4 f0 = fp[0], f1 = fp[1];
#pragma unroll
                    for (int j = 0; j < 4; ++j) {
                        av[j]     = (__bf16)(f0[j] * eps1 + g0[j]);
                        av[j + 4] = (__bf16)(f1[j] * eps1 + g1[j]);
                    }
                } else {
                    bf16x8 fv = *(const bf16x8*)((const bf16_t*)feat + base);
#pragma unroll
                    for (int j = 0; j < 4; ++j) {
                        av[j]     = (__bf16)((float)fv[j]     * eps1 + g0[j]);
                        av[j + 4] = (__bf16)((float)fv[j + 4] * eps1 + g1[j]);
                    }
                }
            } else {
#pragma unroll
                for (int j = 0; j < 8; ++j) av[j] = (__bf16)0.f;
            }
            *(bf16x8*)&At[row * 136 + k0] = av;
        }
        __syncthreads();

        bf16x8 a[4];
#pragma unroll
        for (int kk = 0; kk < 4; ++kk)
            a[kk] = *(const bf16x8*)&At[r * 136 + kk * 32 + quad * 8];

        bf16x8 wfa[4], wfb[4];
#pragma unroll
        for (int kk = 0; kk < 4; ++kk) {
            wfa[kk] = pw1v[(ct0 * 4 + kk) * 64 + lane];
            wfb[kk] = pw1v[(ct1 * 4 + kk) * 64 + lane];
        }
        float b1a = ldf(b1, ct0 * 16 + r, fB1);
        float b1b = ldf(b1, ct1 * 16 + r, fB1);
        {
            f32x4 acc = {0.f, 0.f, 0.f, 0.f};
#pragma unroll
            for (int kk = 0; kk < 4; ++kk)
                acc = __builtin_amdgcn_mfma_f32_16x16x32_bf16(a[kk], wfa[kk], acc, 0, 0, 0);
#pragma unroll
            for (int gg = 0; gg < 4; ++gg)
                H1[(quad * 4 + gg) * 136 + ct0 * 16 + r] = (__bf16)lrelu(acc[gg] + b1a);
        }
        {
            f32x4 acc = {0.f, 0.f, 0.f, 0.f};
#pragma unroll
            for (int kk = 0; kk < 4; ++kk)
                acc = __builtin_amdgcn_mfma_f32_16x16x32_bf16(a[kk], wfb[kk], acc, 0, 0, 0);
#pragma unroll
            for (int gg = 0; gg < 4; ++gg)
                H1[(quad * 4 + gg) * 136 + ct1 * 16 + r] = (__bf16)lrelu(acc[gg] + b1b);
        }
        __syncthreads();

        bf16x8 a2[4];
#pragma unroll
        for (int kk = 0; kk < 4; ++kk)
            a2[kk] = *(const bf16x8*)&H1[r * 136 + kk * 32 + quad * 8];

#pragma unroll
        for (int kk = 0; kk < 4; ++kk) {
            wfa[kk] = pw2v[(ct0 * 4 + kk) * 64 + lane];
            wfb[kk] = pw2v[(ct1 * 4 + kk) * 64 + lane];
        }
        float b2a = ldf(b2, ct0 * 16 + r, fB2);
        float b2b = ldf(b2, ct1 * 16 + r, fB2);

#pragma unroll
        for (int cp = 0; cp < 2; ++cp) {
            const int ct = cp ? ct1 : ct0;
            f32x4 acc = {0.f, 0.f, 0.f, 0.f};
#pragma unroll
            for (int kk = 0; kk < 4; ++kk)
                acc = __builtin_amdgcn_mfma_f32_16x16x32_bf16(
                    a2[kk], cp ? wfb[kk] : wfa[kk], acc, 0, 0, 0);
            float bias = cp ? b2b : b2a;
#pragma unroll
            for (int gg = 0; gg < 4; ++gg) {
                int row = rowBase + quad * 4 + gg;
                float v = lrelu(acc[gg] + bias);
                if (HOUT)
                    At[(quad * 4 + gg) * 136 + ct * 16 + r] = (__bf16)v;
                if (row < N) {
                    int col = ct * 16 + r;
                    if (RESIDUAL) v += ldf(feat, (size_t)row * DDIM + col, fF);
                    out[(size_t)row * DDIM + col] = v;
                }
            }
        }

        if (HOUT) {
            __syncthreads();
            int row = tid >> 4;
            int k0  = (tid & 15) * 8;
            int g   = rowBase + row;
            if (g < N)
                *(bf16x8*)&hout[(size_t)g * DDIM + k0] =
                    *(const bf16x8*)&At[row * 136 + k0];
        }
        __syncthreads();   // LDS safe for next tile
    }
}

// ======================= cooperative megakernel =============================
struct MegaArgs {
    TensorTab T;
    WPtrs P;
    int* flags;
    __bf16* wfp;
    const void* featRow;    // d_in[0]
    const void* featCol;    // d_in[1]
    __bf16* cbX;
    __bf16* cbH;
    const int* srcA; const int* dstA; const void* wA;
    const int* srcB; const int* dstB; const void* wB;
    int nE;
    int* cntA; int* cntB;   // ovCnt at +NROW of each
    int2* sl2A; int2* sl2B;
    int* ovLA; int* ovLB;
    float* out_row; float* out_col;
    const void* b1A; const void* b2A; const void* epsA;
    const void* b1B; const void* b2B; const void* epsB;
    int zn; int n8;
};

__global__ __launch_bounds__(256, 8) void mega(MegaArgs A)
{
    cg::grid_group grid = cg::this_grid();
    __shared__ alignas(16) __bf16 At[16 * 136];
    __shared__ alignas(16) __bf16 H1[16 * 136];
    __shared__ int vb, vf;

    const int tid = threadIdx.x;
    const int bid = (int)blockIdx.x;
    const int nB  = (int)gridDim.x;
    const int gthreads = nB * 256;
    const int g = bid * 256 + tid;

    // ---- phase 0: zero counts + detect dtypes ----
    for (int i = g; i < A.zn; i += gthreads) A.cntA[i] = 0;
    if (bid < 18) {
        const int t = bid;
        if (tid == 0) { vb = 0; vf = 0; }
        __syncthreads();
        const int n = A.T.n[t];
        const bool isFloatArr = (t != 2 && t != 3 && t != 5 && t != 6) && n >= 2;
        if (isFloatArr) {
            int nw = n / 2;
            int wi = (int)(((long long)tid * nw) >> 8);
            unsigned w = ((const unsigned*)A.T.p[t])[wi];
            unsigned low = w & 0xffffu;
            if (low) {
                int e = (int)((low >> 7) & 0xffu);
                if (e >= 90 && e <= 141) atomicAdd(&vb, 1);
                else                     atomicAdd(&vf, 1);
            }
        }
        __syncthreads();
        if (tid == 0) A.flags[t] = (isFloatArr && vf > vb) ? 1 : 0;
    }
    grid.sync();

    // ---- phase 1: convert cbX + weight prep (4/7) || fillA (3/7) ----
    {
        int C = (nB * 4) / 7;
        if (C < 1) C = 1;
        if (C >= nB) C = nB - 1;
        if (bid < C) {
            int lg = bid * 256 + tid, lt = C * 256;
            bool fX = dtf(A.flags, 1);
            for (int i = lg; i < A.n8; i += lt)
                convert_one(A.featCol, A.cbX, i, A.n8, fX);
            for (int s = lg; s < 4 * 2048; s += lt)
                prep_one(A.P, A.flags, A.wfp, s);
        } else {
            int lg = (bid - C) * 256 + tid, lt = (nB - C) * 256;
            bool fW = dtf(A.flags, 4);
            for (int e = lg; e < A.nE; e += lt)
                fill_edges(e, A.dstA, A.srcA, A.wA, A.nE, A.cntA, A.sl2A,
                           A.cntA + NROW, A.ovLA, fW);
        }
    }
    grid.sync();

    // ---- phase 2: segsumA (4/7) || fillB (3/7) ----
    {
        int S = (nB * 4) / 7;
        if (S < 1) S = 1;
        if (S >= nB) S = nB - 1;
        if (bid < S) {
            seg_rows(bid, S, A.cbX, A.cntA, A.sl2A, A.out_col, NROW,
                     A.srcA, A.dstA, A.wA, A.ovLA, A.cntA + NROW,
                     A.flags, 4, tid);
        } else {
            int lg = (bid - S) * 256 + tid, lt = (nB - S) * 256;
            bool fW = dtf(A.flags, 7);
            for (int e = lg; e < A.nE; e += lt)
                fill_edges(e, A.dstB, A.srcB, A.wB, A.nE, A.cntB, A.sl2B,
                           A.cntB + NROW, A.ovLB, fW);
        }
    }
    grid.sync();

    // ---- phase 3: mlp1 (out_row = h+feat_row f32, cbH = h bf16) ----
    mlp_tiles<true, true>(bid, nB, At, H1, A.featRow, A.out_col,
                          A.b1A, A.b2A, A.epsA, A.out_row, NROW,
                          A.flags, 0, 9, 11, 16,
                          A.wfp + 0 * 16384, A.wfp + 1 * 16384, A.cbH, tid);
    grid.sync();

    // ---- phase 4: segsumB ----
    seg_rows(bid, nB, A.cbH, A.cntB, A.sl2B, A.out_col, NCOL,
             A.srcB, A.dstB, A.wB, A.ovLB, A.cntB + NROW, A.flags, 7, tid);
    grid.sync();

    // ---- phase 5: mlp2 -> out_col ----
    mlp_tiles<true, false>(bid, nB, At, H1, A.featCol, A.out_col,
                           A.b1B, A.b2B, A.epsB, A.out_col, NCOL,
                           A.flags, 1, 13, 15, 17,
                           A.wfp + 2 * 16384, A.wfp + 3 * 16384, nullptr, tid);
}

// ======================= r14 fallback kernels (proven, 299.9us) =============
__global__ __launch_bounds__(256) void detect_zero(TensorTab T, int* flags,
                                                   int* z, int zn)
{
    const int tid = threadIdx.x;
    if (blockIdx.x >= 18) {
        int i = (blockIdx.x - 18) * 256 + tid;
        if (i < zn) z[i] = 0;
        return;
    }
    __shared__ int vb, vf;
    const int t = blockIdx.x;
    if (tid == 0) { vb = 0; vf = 0; }
    __syncthreads();
    const int n = T.n[t];
    const bool isFloatArr = (t != 2 && t != 3 && t != 5 && t != 6) && n >= 2;
    if (isFloatArr) {
        int nw = n / 2;
        int wi = (int)(((long long)tid * nw) >> 8);
        unsigned w = ((const unsigned*)T.p[t])[wi];
        unsigned low = w & 0xffffu;
        if (low) {
            int e = (int)((low >> 7) & 0xffu);
            if (e >= 90 && e <= 141) atomicAdd(&vb, 1);
            else                     atomicAdd(&vf, 1);
        }
    }
    __syncthreads();
    if (tid == 0) flags[t] = (isFloatArr && vf > vb) ? 1 : 0;
}

__global__ __launch_bounds__(1024) void prep_fill_i2(
    WPtrs P, const int* __restrict__ flags, __bf16* __restrict__ wfp,
    const void* __restrict__ feat, __bf16* __restrict__ cbuf, int n8,
    int fiFeat, int cb, int eb, int K7,
    const int* __restrict__ f_dst, const int* __restrict__ f_src,
    const void* __restrict__ f_w, int f_nE, int* __restrict__ f_counts,
    int2* __restrict__ f_slots2, int* __restrict__ f_ovCnt,
    int* __restrict__ f_ovList, int f_fiW)
{
    const int g = blockIdx.x;
    const int tid = threadIdx.x;
    if (g >= K7) {
        prep_one(P, flags, wfp, (g - K7) * 1024 + tid);
        return;
    }
    int grp = g / 7, rem = g % 7;
    if (rem < 4) {
        int b = grp * 4 + rem;
        if (b >= cb) return;
        convert_one(feat, cbuf, b * 1024 + tid, n8, dtf(flags, fiFeat));
    } else {
        int b = grp * 3 + (rem - 4);
        if (b >= eb) return;
        fill_edges(b * 1024 + tid, f_dst, f_src, f_w, f_nE, f_counts,
                   f_slots2, f_ovCnt, f_ovList, dtf(flags, f_fiW));
    }
}

__global__ __launch_bounds__(256) void segsum_fill_i(
    const __bf16* __restrict__ gsrc, const int* __restrict__ counts,
    const int2* __restrict__ slots2, float* __restrict__ agg, int nRows,
    const int* __restrict__ srcArr, const int* __restrict__ dstArr,
    const void* __restrict__ wArr, const int* __restrict__ ovList,
    const int* __restrict__ ovCount, const int* __restrict__ flags, int fiW,
    int segBlocks, int fillBlocks,
    const int* __restrict__ f_dst, const int* __restrict__ f_src,
    const void* __restrict__ f_w, int f_nE, int* __restrict__ f_counts,
    int2* __restrict__ f_slots2, int* __restrict__ f_ovCnt,
    int* __restrict__ f_ovList, int f_fiW)
{
    const int tid = threadIdx.x;
    int bid;
    if (f_dst) {
        int grp = (int)blockIdx.x / 7, rem = (int)blockIdx.x % 7;
        if (rem >= 4) {
            int b = grp * 3 + (rem - 4);
            if (b < fillBlocks)
                fill_edges(b * 256 + tid, f_dst, f_src, f_w, f_nE, f_counts,
                           f_slots2, f_ovCnt, f_ovList, dtf(flags, f_fiW));
            return;
        }
        bid = grp * 4 + rem;
        if (bid >= segBlocks) return;
    } else {
        bid = blockIdx.x;
        if (bid >= segBlocks) return;
    }
    seg_rows(bid, 0x40000000, gsrc, counts, slots2, agg, nRows, srcArr,
             dstArr, wArr, ovList, ovCount, flags, fiW, tid);
    // (stride huge -> exactly one seg-block; reuse shared body)
}

template <bool RESIDUAL, bool HOUT>
__global__ __launch_bounds__(256) void mlp_cs(
    const void* __restrict__ feat, const float* __restrict__ agg,
    const void* __restrict__ b1, const void* __restrict__ b2,
    const void* __restrict__ epsp, float* __restrict__ out, int N,
    const int* __restrict__ flags, int fiFeat, int fiB1, int fiB2, int fiEps,
    const __bf16* __restrict__ pW1, const __bf16* __restrict__ pW2,
    __bf16* __restrict__ hout,
    int mblocks,
    const int* __restrict__ f_dst, const int* __restrict__ f_src,
    const void* __restrict__ f_w, int f_nE, int* __restrict__ f_counts,
    int2* __restrict__ f_slots2, int* __restrict__ f_ovCnt,
    int* __restrict__ f_ovList, int f_fiW)
{
    __shared__ alignas(16) __bf16 At[16 * 136];
    __shared__ alignas(16) __bf16 H1[16 * 136];
    const int tid = threadIdx.x;
    if (f_dst && (int)blockIdx.x >= mblocks) {
        int e = ((int)blockIdx.x - mblocks) * 256 + tid;
        fill_edges(e, f_dst, f_src, f_w, f_nE, f_counts, f_slots2,
                   f_ovCnt, f_ovList, dtf(flags, f_fiW));
        return;
    }
    if ((int)blockIdx.x >= mblocks) return;
    mlp_tiles<RESIDUAL, HOUT>((int)blockIdx.x, 0x40000000, At, H1, feat, agg,
                              b1, b2, epsp, out, N, flags,
                              fiFeat, fiB1, fiB2, fiEps, pW1, pW2, hout, tid);
}

// ======================= legacy kernels (ws-too-small) ======================
__global__ __launch_bounds__(256) void scatter_any(
    const void* __restrict__ feat, const int* __restrict__ src,
    const int* __restrict__ dst, const void* __restrict__ w,
    float* __restrict__ agg, int nE,
    const int* __restrict__ flags, int fiFeat, int fiW)
{
    const bool fF = dtf(flags, fiFeat);
    const bool fW = dtf(flags, fiW);
    int g = blockIdx.x * 256 + threadIdx.x;
    int e = g >> 5;
    if (e >= nE) return;
    int c = (g & 31) << 2;
    int s = src[e], d = dst[e];
    float wf = ldf(w, e, fW);
    size_t base = (size_t)s * DDIM + c;
    float* ap = agg + (size_t)d * DDIM + c;
    unsafeAtomicAdd(ap + 0, ldf(feat, base + 0, fF) * wf);
    unsafeAtomicAdd(ap + 1, ldf(feat, base + 1, fF) * wf);
    unsafeAtomicAdd(ap + 2, ldf(feat, base + 2, fF) * wf);
    unsafeAtomicAdd(ap + 3, ldf(feat, base + 3, fF) * wf);
}

__global__ __launch_bounds__(256) void residual_add(
    float* __restrict__ out, const void* __restrict__ feat, int n4,
    const int* __restrict__ flags, int fiFeat)
{
    const bool fF = flags[fiFeat] != 0;
    int i = blockIdx.x * 256 + threadIdx.x;
    if (i >= n4) return;
    f32x4 o = ((const f32x4*)out)[i];
    f32x4 r;
#pragma unroll
    for (int j = 0; j < 4; ++j) r[j] = o[j] + ldf(feat, (size_t)i * 4 + j, fF);
    ((f32x4*)out)[i] = r;
}

__device__ __forceinline__ void fill_wfrag(const void* __restrict__ W, bool f,
                                           __bf16* wf, int tid)
{
#pragma unroll
    for (int i = 0; i < 8; ++i) {
        int sIdx  = tid + i * 256;
        int l     = sIdx & 63;
        int combo = sIdx >> 6;
        int ct = combo >> 2, kk = combo & 3;
        int col  = ct * 16 + (l & 15);
        int krow = kk * 32 + (l >> 4) * 8;
        __bf16* dp = wf + (size_t)sIdx * 8;
#pragma unroll
        for (int j = 0; j < 8; ++j)
            dp[j] = (__bf16)ldf(W, (size_t)(krow + j) * DDIM + col, f);
    }
}

template <bool RESIDUAL>
__global__ __launch_bounds__(256) void mlp_kernel(
    const void* __restrict__ feat, const float* __restrict__ agg,
    const void* __restrict__ W1, const void* __restrict__ b1,
    const void* __restrict__ W2, const void* __restrict__ b2,
    const void* __restrict__ epsp, float* __restrict__ out, int N,
    const int* __restrict__ flags,
    int fiFeat, int fiW1, int fiB1, int fiW2, int fiB2, int fiEps)
{
    __shared__ alignas(16) __bf16 wf[32 * 64 * 8];
    __shared__ alignas(16) __bf16 h1t[64 * 136];

    const bool fF  = flags[fiFeat] != 0;
    const bool fB1 = flags[fiB1] != 0;
    const bool fB2 = flags[fiB2] != 0;
    const bool fE  = flags[fiEps] != 0;

    const int tid  = threadIdx.x;
    const int lane = tid & 63;
    const int wave = tid >> 6;
    const int quad = lane >> 4;
    const int r    = lane & 15;

    fill_wfrag(W1, flags[fiW1] != 0, wf, tid);

    const float eps1 = 1.f + ldf(epsp, 0, fE);
    const int rowBase = blockIdx.x * 64 + wave * 16;

    bf16x8 a[4];
    {
        int rowA = rowBase + r;
        if (rowA < N) {
            size_t fb = (size_t)rowA * DDIM + quad * 8;
            const f32x4* gp = (const f32x4*)(agg + fb);
            if (fF) {
                const f32x4* fp = (const f32x4*)((const float*)feat + fb);
#pragma unroll
                for (int kk = 0; kk < 4; ++kk) {
                    f32x4 f0 = fp[kk * 8], f1 = fp[kk * 8 + 1];
                    f32x4 g0 = gp[kk * 8], g1 = gp[kk * 8 + 1];
                    bf16x8 av;
#pragma unroll
                    for (int j = 0; j < 4; ++j) {
                        av[j]     = (__bf16)(f0[j] * eps1 + g0[j]);
                        av[j + 4] = (__bf16)(f1[j] * eps1 + g1[j]);
                    }
                    a[kk] = av;
                }
            } else {
                const bf16x8* fp = (const bf16x8*)((const bf16_t*)feat + fb);
#pragma unroll
                for (int kk = 0; kk < 4; ++kk) {
                    bf16x8 fv = fp[kk * 4];
                    f32x4 g0 = gp[kk * 8], g1 = gp[kk * 8 + 1];
                    bf16x8 av;
#pragma unroll
                    for (int j = 0; j < 4; ++j) {
                        av[j]     = (__bf16)((float)fv[j]     * eps1 + g0[j]);
                        av[j + 4] = (__bf16)((float)fv[j + 4] * eps1 + g1[j]);
                    }
                    a[kk] = av;
                }
            }
        } else {
#pragma unroll
            for (int kk = 0; kk < 4; ++kk)
#pragma unroll
                for (int j = 0; j < 8; ++j) a[kk][j] = (__bf16)0.f;
        }
    }

    __syncthreads();

    const bf16x8* wv = (const bf16x8*)wf;
#pragma unroll
    for (int ct = 0; ct < 8; ++ct) {
        f32x4 acc = {0.f, 0.f, 0.f, 0.f};
#pragma unroll
        for (int kk = 0; kk < 4; ++kk)
            acc = __builtin_amdgcn_mfma_f32_16x16x32_bf16(
                a[kk], wv[(ct * 4 + kk) * 64 + lane], acc, 0, 0, 0);
        float bias = ldf(b1, ct * 16 + r, fB1);
#pragma unroll
        for (int gg = 0; gg < 4; ++gg)
            h1t[(wave * 16 + quad * 4 + gg) * 136 + ct * 16 + r] =
                (__bf16)lrelu(acc[gg] + bias);
    }
    __syncthreads();

    bf16x8 a2[4];
#pragma unroll
    for (int kk = 0; kk < 4; ++kk)
        a2[kk] = *(const bf16x8*)&h1t[(wave * 16 + r) * 136 + kk * 32 + quad * 8];

    fill_wfrag(W2, flags[fiW2] != 0, wf, tid);
    __syncthreads();

#pragma unroll
    for (int ct = 0; ct < 8; ++ct) {
        f32x4 acc = {0.f, 0.f, 0.f, 0.f};
#pragma unroll
        for (int kk = 0; kk < 4; ++kk)
            acc = __builtin_amdgcn_mfma_f32_16x16x32_bf16(
                a2[kk], wv[(ct * 4 + kk) * 64 + lane], acc, 0, 0, 0);
        float bias = ldf(b2, ct * 16 + r, fB2);
#pragma unroll
        for (int gg = 0; gg < 4; ++gg) {
            int row = rowBase + quad * 4 + gg;
            if (row < N) {
                int col = ct * 16 + r;
                float v = lrelu(acc[gg] + bias);
                if (RESIDUAL) v += ldf(feat, (size_t)row * DDIM + col, fF);
                out[(size_t)row * DDIM + col] = v;
            }
        }
    }
}

extern "C" void kernel_launch(void* const* d_in, const int* in_sizes, int n_in,
                              void* d_out, int out_size, void* d_ws, size_t ws_size,
                              hipStream_t stream)
{
    const int* src_c2r = (const int*)d_in[2];
    const int* dst_c2r = (const int*)d_in[3];
    const int* src_r2c = (const int*)d_in[5];
    const int* dst_r2c = (const int*)d_in[6];
    const int nE = in_sizes[2];

    char* wsb = (char*)d_ws;
    int*    flags  = (int*)wsb;
    __bf16* wfprep = (__bf16*)(wsb + 128);

    // ---- A8 layout: cntA|ovCntA|cntB|ovCntB|slots2A|slots2B|ovLA|ovLB|cbufX|cbufH
    int*    cntA   = (int*)(wsb + 128 + 131072);
    int*    cntB   = cntA + NROW + 8;
    size_t  o5 = 128 + 131072 + ((size_t)2 * NROW + 16) * 4;
    o5 = (o5 + 15) & ~(size_t)15;
    int2*   sl2A = (int2*)(wsb + o5);  o5 += (size_t)NROW * CAP * 8;
    int2*   sl2B = (int2*)(wsb + o5);  o5 += (size_t)NROW * CAP * 8;
    int*    ovLA = (int*)(wsb + o5);   o5 += (size_t)nE * 4;
    int*    ovLB = (int*)(wsb + o5);   o5 += (size_t)nE * 4;
    o5 = (o5 + 15) & ~(size_t)15;
    __bf16* cbX  = (__bf16*)(wsb + o5); o5 += (size_t)NCOL * DDIM * 2;
    __bf16* cbH  = (__bf16*)(wsb + o5); o5 += (size_t)NROW * DDIM * 2;
    const size_t NEED_A8 = o5;
    const bool tierA8 = ws_size >= NEED_A8;

    TensorTab T;
    for (int i = 0; i < 18; ++i) { T.p[i] = d_in[i]; T.n[i] = in_sizes[i]; }

    float* out_row = (float*)d_out;
    float* out_col = out_row + (size_t)NROW * DDIM;
    const size_t aggBytes = (size_t)NROW * DDIM * sizeof(float);

    const int eblocks  = (nE + 255) / 256;
    const int sblocks  = (nE * 32 + 255) / 256;
    const int mblocksR = (NROW + 63) / 64;
    const int mblocksC = (NCOL + 63) / 64;
    const int csR      = (NROW + 15) / 16;
    const int csC      = (NCOL + 15) / 16;
    const int gblocksR = (NROW + 3) / 4;
    const int gblocksC = (NCOL + 3) / 4;
    const int zn2      = 2 * NROW + 16;
    const int zb2      = (zn2 + 255) / 256;

    WPtrs P;
    P.W[0] = d_in[8];  P.fi[0] = 8;
    P.W[1] = d_in[10]; P.fi[1] = 10;
    P.W[2] = d_in[12]; P.fi[2] = 12;
    P.W[3] = d_in[14]; P.fi[3] = 14;

    // ---- attempt single cooperative megakernel (kills ~12us/dispatch) ----
    if (tierA8) {
        int coopAttr = 0, nCU = 0, maxB = 0;
        hipDeviceGetAttribute(&coopAttr, hipDeviceAttributeCooperativeLaunch, 0);
        hipDeviceGetAttribute(&nCU, hipDeviceAttributeMultiprocessorCount, 0);
        hipOccupancyMaxActiveBlocksPerMultiprocessor(&maxB, (const void*)mega,
                                                     256, 0);
        if (coopAttr && nCU > 0 && maxB > 0 && (long long)maxB * nCU >= 64) {
            MegaArgs A;
            A.T = T; A.P = P;
            A.flags = flags; A.wfp = wfprep;
            A.featRow = d_in[0]; A.featCol = d_in[1];
            A.cbX = cbX; A.cbH = cbH;
            A.srcA = src_c2r; A.dstA = dst_c2r; A.wA = d_in[4];
            A.srcB = src_r2c; A.dstB = dst_r2c; A.wB = d_in[7];
            A.nE = nE;
            A.cntA = cntA; A.cntB = cntB;
            A.sl2A = sl2A; A.sl2B = sl2B;
            A.ovLA = ovLA; A.ovLB = ovLB;
            A.out_row = out_row; A.out_col = out_col;
            A.b1A = d_in[9];  A.b2A = d_in[11]; A.epsA = d_in[16];
            A.b1B = d_in[13]; A.b2B = d_in[15]; A.epsB = d_in[17];
            A.zn = zn2; A.n8 = NCOL * DDIM / 8;
            void* kargs[] = { (void*)&A };
            hipError_t err = hipLaunchCooperativeKernel(
                (const void*)mega, dim3((unsigned)(maxB * nCU)), dim3(256),
                kargs, 0, stream);
            if (err == hipSuccess) return;
            (void)hipGetLastError();   // clear sticky error, fall back
        }
    }

    if (tierA8) {
        // r14 proven path (299.9 us)
        const int n8  = NCOL * DDIM / 8;
        const int cb4 = (n8 + 1023) / 1024;
        const int eb4 = (nE + 1023) / 1024;
        detect_zero<<<18 + zb2, 256, 0, stream>>>(T, flags, cntA, zn2);
        {
            int ka = (cb4 + 3) / 4, kb = (eb4 + 2) / 3;
            int K = ka > kb ? ka : kb;
            prep_fill_i2<<<7 * K + 8, 1024, 0, stream>>>(
                P, flags, wfprep, d_in[1], cbX, n8, 1, cb4, eb4, 7 * K,
                dst_c2r, src_c2r, d_in[4], nE, cntA, sl2A, cntA + NROW, ovLA, 4);
        }
        {
            int ka = (gblocksR + 3) / 4, kb = (eblocks + 2) / 3;
            int K = ka > kb ? ka : kb;
            segsum_fill_i<<<7 * K, 256, 0, stream>>>(
                cbX, cntA, sl2A, out_col, NROW, src_c2r, dst_c2r, d_in[4],
                ovLA, cntA + NROW, flags, 4,
                gblocksR, eblocks, dst_r2c, src_r2c, d_in[7], nE, cntB,
                sl2B, cntB + NROW, ovLB, 7);
        }
        mlp_cs<true, true><<<csR, 256, 0, stream>>>(
            d_in[0], out_col, d_in[9], d_in[11], d_in[16],
            out_row, NROW, flags, 0, 9, 11, 16,
            wfprep + 0 * 16384, wfprep + 1 * 16384, cbH,
            csR, nullptr, nullptr, nullptr, 0, nullptr, nullptr,
            nullptr, nullptr, 0);
        segsum_fill_i<<<gblocksC, 256, 0, stream>>>(
            cbH, cntB, sl2B, out_col, NCOL, src_r2c, dst_r2c, d_in[7],
            ovLB, cntB + NROW, flags, 7,
            gblocksC, 0, nullptr, nullptr, nullptr, 0, nullptr,
            nullptr, nullptr, nullptr, 0);
        mlp_cs<true, false><<<csC, 256, 0, stream>>>(
            d_in[1], out_col, d_in[13], d_in[15], d_in[17],
            out_col, NCOL, flags, 1, 13, 15, 17,
            wfprep + 2 * 16384, wfprep + 3 * 16384, nullptr,
            csC, nullptr, nullptr, nullptr, 0, nullptr, nullptr,
            nullptr, nullptr, 0);
    } else {
        // legacy path
        detect_zero<<<18, 256, 0, stream>>>(T, flags, nullptr, 0);
        hipMemsetAsync(out_col, 0, aggBytes, stream);
        scatter_any<<<sblocks, 256, 0, stream>>>(d_in[1], src_c2r, dst_c2r,
            d_in[4], out_col, nE, flags, 1, 4);
        mlp_kernel<false><<<mblocksR, 256, 0, stream>>>(
            d_in[0], out_col, d_in[8], d_in[9], d_in[10], d_in[11], d_in[16],
            out_row, NROW, flags, 0, 8, 9, 10, 11, 16);

        hipMemsetAsync(out_col, 0, aggBytes, stream);
        scatter_any<<<sblocks, 256, 0, stream>>>(out_row, src_r2c, dst_r2c,
            d_in[7], out_col, nE, flags, -1, 7);
        residual_add<<<(NROW * DDIM / 4 + 255) / 256, 256, 0, stream>>>(
            out_row, d_in[0], NROW * DDIM / 4, flags, 0);
        mlp_kernel<true><<<mblocksC, 256, 0, stream>>>(
            d_in[1], out_col, d_in[12], d_in[13], d_in[14], d_in[15], d_in[17],
            out_col, NCOL, flags, 1, 12, 13, 14, 15, 17);
    }
}